// Round 6
// baseline (81.731 us; speedup 1.0000x reference)
//
#include <hip/hip_runtime.h>

#define N_ROWS 16384
#define L_DIM  4096
#define CG     32                 // locations per block (128B/row staging reads)
#define JT     256                // output-j columns per block (1 float4/lane)
#define NBKT   (L_DIM / CG)       // 128
#define NJT    (L_DIM / JT)       // 16
#define PITCH  (JT + 4)           // 1040B rows: 16B-aligned, conflict-free b128 reads
#define CAP    512                // list capacity (bucket ~Poisson(128), max ~180)

// out[i, j] = z[i, w[i]] * W[j, w[i]] + b[j]
// Block (g, t): locations l0=g*CG.., j-range j0=t*JT..
// LDS = 37.4 KB -> 4 blocks/CU: staggered blocks keep the store pipe busy
// during other blocks' stage/scan prologues (R5 post-mortem: phase alignment
// at 2 blocks/CU left HBM write idle ~30% of the time).
__global__ __launch_bounds__(256, 4) void pnet_fused(
    const int* __restrict__ w,
    const float* __restrict__ z,
    const float* __restrict__ W,
    const float* __restrict__ b,
    float* __restrict__ out)
{
    __shared__ float tile[CG * PITCH];   // tile[c*PITCH + r] = W[j0+r][l0+c]
    __shared__ int   list[CAP];          // i | (c<<16)
    __shared__ float zlist[CAP];
    __shared__ int   cnt;

    const int tid  = threadIdx.x;
    const int l0   = blockIdx.x * CG;
    const int j0   = blockIdx.y * JT;
    const int wid  = tid >> 6;
    const int lane = tid & 63;

    if (tid == 0) cnt = 0;

    const float4 bbv = *(const float4*)&b[j0 + lane * 4];

    __syncthreads();  // cnt ready

    // ---- stage W tile: 128B-per-row coalesced float4 reads (full L2 lines),
    //      transposed scalar LDS writes (4-way banked = 1.58x, negligible) ----
    {
        const int q     = tid & 7;        // 16B chunk within the 128B row segment
        const int rbase = tid >> 3;       // row 0..31, step 32
        #pragma unroll
        for (int it = 0; it < JT / 32; ++it) {
            const int r = rbase + it * 32;
            const float4 v = *(const float4*)&W[(size_t)(j0 + r) * L_DIM + l0 + 4 * q];
            tile[(4 * q + 0) * PITCH + r] = v.x;
            tile[(4 * q + 1) * PITCH + r] = v.y;
            tile[(4 * q + 2) * PITCH + r] = v.z;
            tile[(4 * q + 3) * PITCH + r] = v.w;
        }
    }

    // ---- scan w[] once: append packed entries (L2/L3-fast, no gathers) ----
    #pragma unroll
    for (int s = 0; s < N_ROWS / 1024; ++s) {
        const int i0  = s * 1024 + tid * 4;
        const int4 wv = *(const int4*)&w[i0];
        const int vals[4] = {wv.x, wv.y, wv.z, wv.w};
        #pragma unroll
        for (int e = 0; e < 4; ++e) {
            const unsigned c = (unsigned)(vals[e] - l0);
            if (c < CG) {
                const int pos = atomicAdd(&cnt, 1);
                if (pos < CAP) list[pos] = (i0 + e) | ((int)c << 16);
            }
        }
    }

    __syncthreads();  // tile + list ready
    const int n     = cnt;
    const int nmain = n < CAP ? n : CAP;

    // ---- cooperative zw gather: all of the block's loads in flight at once ----
    for (int e = tid; e < nmain; e += 256) {
        const int ent = list[e];
        zlist[e] = z[(unsigned)((ent & 0xFFFF) * L_DIM) + (unsigned)(ent >> 16) + l0];
    }
    __syncthreads();  // zlist ready

    // ---- stream matched rows: 1 ds_read_b128 + 4 fma + 1KB store per row ----
    for (int e = wid; e < nmain; e += 4) {
        const int   ent = list[e];
        const int   i   = ent & 0xFFFF;
        const int   c   = ent >> 16;
        const float zw  = zlist[e];
        const float4 wv4 = *(const float4*)&tile[c * PITCH + lane * 4];
        float4 o;
        o.x = fmaf(zw, wv4.x, bbv.x);
        o.y = fmaf(zw, wv4.y, bbv.y);
        o.z = fmaf(zw, wv4.z, bbv.z);
        o.w = fmaf(zw, wv4.w, bbv.w);
        *(float4*)&out[(unsigned)(i * L_DIM) + j0 + lane * 4] = o;
    }

    // ---- overflow fallback (unreachable for this input; kept for correctness) ----
    if (n > CAP) {
        for (int p = 0; p < N_ROWS / 512; ++p) {
            __syncthreads();
            if (tid == 0) cnt = 0;
            __syncthreads();
            const int i0  = p * 512 + tid * 2;
            const int2 wv = *(const int2*)&w[i0];
            const int vals[2] = {wv.x, wv.y};
            #pragma unroll
            for (int e = 0; e < 2; ++e) {
                const unsigned c = (unsigned)(vals[e] - l0);
                if (c < CG) {
                    const int pos = atomicAdd(&cnt, 1);   // <=512 per pass == CAP
                    list[pos]  = (i0 + e) | ((int)c << 16);
                    zlist[pos] = z[(unsigned)((i0 + e) * L_DIM) + vals[e]];
                }
            }
            __syncthreads();
            const int np = cnt;
            for (int e = wid; e < np; e += 4) {
                const int   ent = list[e];
                const int   i   = ent & 0xFFFF;
                const int   c   = ent >> 16;
                const float zw  = zlist[e];
                const float4 wv4 = *(const float4*)&tile[c * PITCH + lane * 4];
                float4 o;
                o.x = fmaf(zw, wv4.x, bbv.x);
                o.y = fmaf(zw, wv4.y, bbv.y);
                o.z = fmaf(zw, wv4.z, bbv.z);
                o.w = fmaf(zw, wv4.w, bbv.w);
                *(float4*)&out[(unsigned)(i * L_DIM) + j0 + lane * 4] = o;
            }
        }
    }
}

extern "C" void kernel_launch(void* const* d_in, const int* in_sizes, int n_in,
                              void* d_out, int out_size, void* d_ws, size_t ws_size,
                              hipStream_t stream) {
    const int*   w = (const int*)d_in[0];
    const float* z = (const float*)d_in[1];
    const float* W = (const float*)d_in[2];
    const float* b = (const float*)d_in[3];
    float* out = (float*)d_out;

    dim3 grid(NBKT, NJT);   // (128, 16) = 2048 blocks
    pnet_fused<<<grid, 256, 0, stream>>>(w, z, W, b, out);
}